// Round 1
// baseline (790.378 us; speedup 1.0000x reference)
//
#include <hip/hip_runtime.h>

#define EPS 1e-5f

// ---------------- Kernel A: bn1 + sign -> int8 b1 [64][1024][196] ----------
__global__ __launch_bounds__(256) void k_bnsign1(
    const float* __restrict__ x,
    const float* __restrict__ g, const float* __restrict__ b,
    const float* __restrict__ m, const float* __restrict__ v,
    char* __restrict__ out, int total4)
{
    int i = blockIdx.x * 256 + threadIdx.x;
    if (i >= total4) return;
    int c = (i / 49) & 1023;              // (i*4)/196 % 1024  (196 = 4*49)
    float sc = g[c] * (1.0f / sqrtf(v[c] + EPS));
    float sh = b[c] - m[c] * sc;
    float4 xv = reinterpret_cast<const float4*>(x)[i];
    float t0 = xv.x * sc + sh;
    float t1 = xv.y * sc + sh;
    float t2 = xv.z * sc + sh;
    float t3 = xv.w * sc + sh;
    char4 o;
    o.x = (t0 > 0.f) ? 1 : ((t0 < 0.f) ? -1 : 0);
    o.y = (t1 > 0.f) ? 1 : ((t1 < 0.f) ? -1 : 0);
    o.z = (t2 > 0.f) ? 1 : ((t2 < 0.f) ? -1 : 0);
    o.w = (t3 > 0.f) ? 1 : ((t3 < 0.f) ? -1 : 0);
    reinterpret_cast<char4*>(out)[i] = o;
}

// ---------------- Kernel B: conv1 1x1 (K=1024 -> CO=256) + relu + bn2 + sign
// GEMM: C[co][m] = sum_k W[co][k] * B1[k][m],  m = n*196+p, M = 12544
// tile 64co x 64m, BK = 32, 256 threads, thread computes 4x4
__global__ __launch_bounds__(256) void k_conv1(
    const char* __restrict__ B1, const float* __restrict__ W,
    const float* __restrict__ g, const float* __restrict__ bb,
    const float* __restrict__ mm, const float* __restrict__ vv,
    char* __restrict__ B2)
{
    const int K = 1024;
    __shared__ float lds_a[32][64];
    __shared__ float lds_b[32][64];
    const int tid = threadIdx.x;
    const int co0 = blockIdx.x * 64;
    const int m0  = blockIdx.y * 64;
    const int co_t = tid & 15, m_t = tid >> 4;

    float acc[4][4] = {};
    for (int k0 = 0; k0 < K; k0 += 32) {
        #pragma unroll
        for (int r = 0; r < 2; ++r) {                  // stage A (weights)
            int f  = r * 256 + tid;                    // 512 float4
            int co = f >> 3, kq = f & 7;
            float4 w4 = *reinterpret_cast<const float4*>(W + (co0 + co) * K + k0 + kq * 4);
            lds_a[kq * 4 + 0][co] = w4.x;
            lds_a[kq * 4 + 1][co] = w4.y;
            lds_a[kq * 4 + 2][co] = w4.z;
            lds_a[kq * 4 + 3][co] = w4.w;
        }
        #pragma unroll
        for (int r = 0; r < 8; ++r) {                  // stage B (signs)
            int e = r * 256 + tid;
            int mloc = e & 63, k = e >> 6;
            int m = m0 + mloc;
            int n = m / 196, p = m - n * 196;
            lds_b[k][mloc] = (float)B1[(n * 1024 + (k0 + k)) * 196 + p];
        }
        __syncthreads();
        #pragma unroll
        for (int k = 0; k < 32; ++k) {
            float4 a4 = *reinterpret_cast<const float4*>(&lds_a[k][co_t * 4]);
            float4 b4 = *reinterpret_cast<const float4*>(&lds_b[k][m_t * 4]);
            float av[4] = {a4.x, a4.y, a4.z, a4.w};
            float bv[4] = {b4.x, b4.y, b4.z, b4.w};
            #pragma unroll
            for (int i = 0; i < 4; ++i)
                #pragma unroll
                for (int j = 0; j < 4; ++j)
                    acc[i][j] = fmaf(av[i], bv[j], acc[i][j]);
        }
        __syncthreads();
    }
    // epilogue: relu -> bn2 -> sign -> int8
    int m = m0 + m_t * 4;
    int n = m / 196, p = m - n * 196;                  // 4 consecutive p, same row
    #pragma unroll
    for (int i = 0; i < 4; ++i) {
        int co = co0 + co_t * 4 + i;
        float sc = g[co] * (1.0f / sqrtf(vv[co] + EPS));
        float sh = bb[co] - mm[co] * sc;
        char o[4];
        #pragma unroll
        for (int j = 0; j < 4; ++j) {
            float h = fmaxf(acc[i][j], 0.0f);
            float t = h * sc + sh;
            o[j] = (t > 0.f) ? 1 : ((t < 0.f) ? -1 : 0);
        }
        *reinterpret_cast<char4*>(B2 + (n * 256 + co) * 196 + p) = make_char4(o[0], o[1], o[2], o[3]);
    }
}

// ---------------- Kernel C: conv2 3x3 pad1 (256->256) + relu + bn3 + sign --
// grid: (8 co-tiles of 32, 64 n), 256 threads
// thread: co_t = tid&7 (4 co each), p_t = tid>>3 (p = p_t + 32*j, j<7)
__global__ __launch_bounds__(256) void k_conv2(
    const char* __restrict__ B2, const float* __restrict__ W,
    const float* __restrict__ g, const float* __restrict__ bb,
    const float* __restrict__ mm, const float* __restrict__ vv,
    char* __restrict__ B3)
{
    __shared__ float tile[8][256];   // [ci][16x16] padded halo
    __shared__ float wl[32][73];     // [co][ci*9+tap], pad 73 vs bank conflicts
    const int tid = threadIdx.x;
    const int co0 = blockIdx.x * 32;
    const int n   = blockIdx.y;
    const int co_t = tid & 7;
    const int p_t  = tid >> 3;

    int sp_base[7];
    #pragma unroll
    for (int j = 0; j < 7; ++j) {
        int p = p_t + 32 * j;
        if (p < 196) { int y = p / 14, xx = p - y * 14; sp_base[j] = y * 16 + xx; }
        else sp_base[j] = 0;
    }

    float acc[4][7] = {};
    for (int ci0 = 0; ci0 < 256; ci0 += 8) {
        #pragma unroll
        for (int r = 0; r < 8; ++r) {                  // input tile + halo
            int e = r * 256 + tid;
            int ci = e >> 8, sp = e & 255;
            int y = sp >> 4, xx = sp & 15;
            float val = 0.f;
            if (y >= 1 && y <= 14 && xx >= 1 && xx <= 14)
                val = (float)B2[(n * 256 + ci0 + ci) * 196 + (y - 1) * 14 + (xx - 1)];
            tile[ci][sp] = val;
        }
        #pragma unroll
        for (int r = 0; r < 9; ++r) {                  // weights 32co x 8ci x 9
            int e = r * 256 + tid;                     // e < 2304 exactly
            int co = e / 72, q = e - co * 72;
            wl[co][q] = W[(co0 + co) * 2304 + ci0 * 9 + q];
        }
        __syncthreads();
        #pragma unroll
        for (int ci = 0; ci < 8; ++ci) {
            #pragma unroll
            for (int tap = 0; tap < 9; ++tap) {
                const int toff = (tap / 3) * 16 + (tap % 3);
                float w[4];
                #pragma unroll
                for (int i = 0; i < 4; ++i) w[i] = wl[co_t * 4 + i][ci * 9 + tap];
                #pragma unroll
                for (int j = 0; j < 7; ++j) {
                    float in = tile[ci][sp_base[j] + toff];
                    #pragma unroll
                    for (int i = 0; i < 4; ++i)
                        acc[i][j] = fmaf(w[i], in, acc[i][j]);
                }
            }
        }
        __syncthreads();
    }
    // epilogue: relu -> bn3 -> sign
    #pragma unroll
    for (int i = 0; i < 4; ++i) {
        int co = co0 + co_t * 4 + i;
        float sc = g[co] * (1.0f / sqrtf(vv[co] + EPS));
        float sh = bb[co] - mm[co] * sc;
        #pragma unroll
        for (int j = 0; j < 7; ++j) {
            int p = p_t + 32 * j;
            if (p < 196) {
                float h = fmaxf(acc[i][j], 0.0f);
                float t = h * sc + sh;
                B3[(n * 256 + co) * 196 + p] = (t > 0.f) ? 1 : ((t < 0.f) ? -1 : 0);
            }
        }
    }
}

// ---------------- Kernel D: conv3 1x1 (K=256 -> CO=1024) + residual + relu -
__global__ __launch_bounds__(256) void k_conv3(
    const char* __restrict__ B3, const float* __restrict__ W,
    const float* __restrict__ x, float* __restrict__ out)
{
    const int K = 256;
    __shared__ float lds_a[32][64];
    __shared__ float lds_b[32][64];
    const int tid = threadIdx.x;
    const int co0 = blockIdx.x * 64;
    const int m0  = blockIdx.y * 64;
    const int co_t = tid & 15, m_t = tid >> 4;

    float acc[4][4] = {};
    for (int k0 = 0; k0 < K; k0 += 32) {
        #pragma unroll
        for (int r = 0; r < 2; ++r) {
            int f  = r * 256 + tid;
            int co = f >> 3, kq = f & 7;
            float4 w4 = *reinterpret_cast<const float4*>(W + (co0 + co) * K + k0 + kq * 4);
            lds_a[kq * 4 + 0][co] = w4.x;
            lds_a[kq * 4 + 1][co] = w4.y;
            lds_a[kq * 4 + 2][co] = w4.z;
            lds_a[kq * 4 + 3][co] = w4.w;
        }
        #pragma unroll
        for (int r = 0; r < 8; ++r) {
            int e = r * 256 + tid;
            int mloc = e & 63, k = e >> 6;
            int m = m0 + mloc;
            int n = m / 196, p = m - n * 196;
            lds_b[k][mloc] = (float)B3[(n * 256 + (k0 + k)) * 196 + p];
        }
        __syncthreads();
        #pragma unroll
        for (int k = 0; k < 32; ++k) {
            float4 a4 = *reinterpret_cast<const float4*>(&lds_a[k][co_t * 4]);
            float4 b4 = *reinterpret_cast<const float4*>(&lds_b[k][m_t * 4]);
            float av[4] = {a4.x, a4.y, a4.z, a4.w};
            float bv[4] = {b4.x, b4.y, b4.z, b4.w};
            #pragma unroll
            for (int i = 0; i < 4; ++i)
                #pragma unroll
                for (int j = 0; j < 4; ++j)
                    acc[i][j] = fmaf(av[i], bv[j], acc[i][j]);
        }
        __syncthreads();
    }
    // epilogue: + residual, relu
    int m = m0 + m_t * 4;
    int n = m / 196, p = m - n * 196;
    #pragma unroll
    for (int i = 0; i < 4; ++i) {
        int co = co0 + co_t * 4 + i;
        size_t idx = (size_t)(n * 1024 + co) * 196 + p;
        float4 r4 = *reinterpret_cast<const float4*>(x + idx);
        float4 o;
        o.x = fmaxf(acc[i][0] + r4.x, 0.f);
        o.y = fmaxf(acc[i][1] + r4.y, 0.f);
        o.z = fmaxf(acc[i][2] + r4.z, 0.f);
        o.w = fmaxf(acc[i][3] + r4.w, 0.f);
        *reinterpret_cast<float4*>(out + idx) = o;
    }
}

extern "C" void kernel_launch(void* const* d_in, const int* in_sizes, int n_in,
                              void* d_out, int out_size, void* d_ws, size_t ws_size,
                              hipStream_t stream) {
    const float* x         = (const float*)d_in[0];
    const float* bn1_gamma = (const float*)d_in[1];
    const float* bn1_beta  = (const float*)d_in[2];
    const float* bn1_mean  = (const float*)d_in[3];
    const float* bn1_var   = (const float*)d_in[4];
    const float* W1        = (const float*)d_in[5];
    const float* bn2_gamma = (const float*)d_in[6];
    const float* bn2_beta  = (const float*)d_in[7];
    const float* bn2_mean  = (const float*)d_in[8];
    const float* bn2_var   = (const float*)d_in[9];
    const float* W2        = (const float*)d_in[10];
    const float* bn3_gamma = (const float*)d_in[11];
    const float* bn3_beta  = (const float*)d_in[12];
    const float* bn3_mean  = (const float*)d_in[13];
    const float* bn3_var   = (const float*)d_in[14];
    const float* W3        = (const float*)d_in[15];
    float* out = (float*)d_out;

    char* b1 = (char*)d_ws;                       // 64*1024*196 = 12,845,056
    char* b2 = b1 + 12845056;                     // 64*256*196  =  3,211,264
    char* b3 = b2 + 3211264;                      // 64*256*196  =  3,211,264

    // A: bn1 + sign
    k_bnsign1<<<12544, 256, 0, stream>>>(x, bn1_gamma, bn1_beta, bn1_mean, bn1_var,
                                         b1, 3211264);
    // B: conv1 1x1 + relu + bn2 + sign
    k_conv1<<<dim3(4, 196), 256, 0, stream>>>(b1, W1, bn2_gamma, bn2_beta,
                                              bn2_mean, bn2_var, b2);
    // C: conv2 3x3 + relu + bn3 + sign
    k_conv2<<<dim3(8, 64), 256, 0, stream>>>(b2, W2, bn3_gamma, bn3_beta,
                                             bn3_mean, bn3_var, b3);
    // D: conv3 1x1 + residual + relu
    k_conv3<<<dim3(16, 196), 256, 0, stream>>>(b3, W3, x, out);
}

// Round 3
// 290.629 us; speedup vs baseline: 2.7195x; 2.7195x over previous
//
#include <hip/hip_runtime.h>

#define EPS 1e-5f

typedef __attribute__((ext_vector_type(8))) short bf16x8;
typedef __attribute__((ext_vector_type(4))) float f32x4;

#define MFMA16(a, b, c) __builtin_amdgcn_mfma_f32_16x16x32_bf16(a, b, c, 0, 0, 0)

__device__ __forceinline__ void gl16(const void* g, void* l) {
    __builtin_amdgcn_global_load_lds(
        (const __attribute__((address_space(1))) unsigned int*)g,
        (__attribute__((address_space(3))) unsigned int*)l, 16, 0, 0);
}

__device__ __forceinline__ unsigned short f2bf(float f) {
    unsigned u = __float_as_uint(f);
    unsigned r = (u + 0x7FFFu + ((u >> 16) & 1u)) >> 16;
    return (unsigned short)r;
}
__device__ __forceinline__ float bf2f(unsigned short h) {
    return __uint_as_float(((unsigned)h) << 16);
}

// ---- sizes ----
// x: [64][1024][196] f32; out same.
// b1  NHWC: [12544][1024] bf16
// b2p NHWC padded: [64][256(sp=16x16)][256(ci)] bf16, 16KB guard margins
// b3  NHWC: [12544][256] bf16
// A1: 3x[256][1024] bf16 splits; A2: 3x[256][2304] (k'=tap*256+ci); A3: [1024][256]

// ---------------- prep: weight splits + layout ----------------
__global__ __launch_bounds__(256) void k_prep(
    const float* __restrict__ W1, const float* __restrict__ W2,
    const float* __restrict__ W3,
    unsigned short* __restrict__ A1, unsigned short* __restrict__ A2,
    unsigned short* __restrict__ A3)
{
    int i = blockIdx.x * 256 + threadIdx.x;
    if (i < 262144) {
        float w = W1[i];
        unsigned short h1 = f2bf(w); float r1 = w - bf2f(h1);
        unsigned short h2 = f2bf(r1); float r2 = r1 - bf2f(h2);
        unsigned short h3 = f2bf(r2);
        A1[i] = h1; A1[262144 + i] = h2; A1[524288 + i] = h3;
        A3[i] = f2bf(W3[i]);
    }
    if (i < 589824) {
        int co = i / 2304, k = i - co * 2304;
        int ci = k / 9, tap = k - ci * 9;
        int o = co * 2304 + tap * 256 + ci;
        float w = W2[i];
        unsigned short h1 = f2bf(w); float r1 = w - bf2f(h1);
        unsigned short h2 = f2bf(r1); float r2 = r1 - bf2f(h2);
        unsigned short h3 = f2bf(r2);
        A2[o] = h1; A2[589824 + o] = h2; A2[1179648 + o] = h3;
    }
}

// ---------------- act1: bn1+sign, NCHW f32 -> NHWC bf16 -------------
__global__ __launch_bounds__(256, 2) void k_act1(
    const float* __restrict__ x,
    const float* __restrict__ g, const float* __restrict__ b,
    const float* __restrict__ mm, const float* __restrict__ vv,
    unsigned short* __restrict__ b1)
{
    __shared__ unsigned short tile[128 * 197];
    __shared__ float ssc[128], ssh[128];
    const int tid = threadIdx.x;
    const int n = blockIdx.x, c0 = blockIdx.y * 128;
    if (tid < 128) {
        int c = c0 + tid;
        float sc = g[c] * (1.0f / sqrtf(vv[c] + EPS));
        ssc[tid] = sc;
        ssh[tid] = b[c] - mm[c] * sc;
    }
    __syncthreads();
    const float* xp = x + ((size_t)n * 1024 + c0) * 196;
    for (int it = 0; it < 98; ++it) {
        int e = it * 256 + tid;
        int c = e / 196, p = e - c * 196;
        float t = xp[e] * ssc[c] + ssh[c];
        tile[c * 197 + p] = (t > 0.f) ? 0x3F80 : ((t < 0.f) ? 0xBF80 : 0);
    }
    __syncthreads();
    const int pr = tid >> 4, cg = (tid & 15) * 8;
    for (int it = 0; it < 13; ++it) {
        int p = it * 16 + pr;
        if (p < 196) {
            unsigned short vals[8];
            #pragma unroll
            for (int j = 0; j < 8; ++j) vals[j] = tile[(cg + j) * 197 + p];
            uint4 pk;
            pk.x = (unsigned)vals[0] | ((unsigned)vals[1] << 16);
            pk.y = (unsigned)vals[2] | ((unsigned)vals[3] << 16);
            pk.z = (unsigned)vals[4] | ((unsigned)vals[5] << 16);
            pk.w = (unsigned)vals[6] | ((unsigned)vals[7] << 16);
            *(uint4*)&b1[((size_t)n * 196 + p) * 1024 + c0 + cg] = pk;
        }
    }
}

// ---------------- zero border ring of b2p ----------------
__global__ __launch_bounds__(256) void k_zb(unsigned short* __restrict__ b2p) {
    int t = blockIdx.x * 256 + threadIdx.x;
    if (t >= 122880) return;
    int ci8 = t & 31;
    int tb = t >> 5;
    int bidx = tb % 60, n = tb / 60;
    int sp;
    if (bidx < 16) sp = bidx;
    else if (bidx < 32) sp = 240 + (bidx - 16);
    else { int s2 = bidx - 32; sp = ((s2 >> 1) + 1) * 16 + (s2 & 1) * 15; }
    ulonglong2 z; z.x = 0; z.y = 0;
    *(ulonglong2*)&b2p[((size_t)(n * 256 + sp)) * 256 + ci8 * 8] = z;
}

// ---------------- gemm1: conv1 1x1, K=1024, 3 splits -> b2p ----------
// BM=64(co) BN=128(m) BK=32; 4 waves: wr=w&1 (32co), wc=w>>1 (64m)
__global__ __launch_bounds__(256, 2) void k_gemm1(
    const unsigned short* __restrict__ A1, const unsigned short* __restrict__ B1,
    const float* __restrict__ g2, const float* __restrict__ be2,
    const float* __restrict__ mu2, const float* __restrict__ va2,
    unsigned short* __restrict__ b2p)
{
    __shared__ unsigned short sA[3][2048];
    __shared__ unsigned short sB[4096];
    const int tid = threadIdx.x;
    const int co0 = blockIdx.x * 64;
    const int m0  = blockIdx.y * 128;
    const int lane = tid & 63, w = tid >> 6;
    const int wr = w & 1, wc = w >> 1;
    const int srow = tid >> 2;
    const int sq = (tid & 3) ^ ((tid >> 3) & 3);
    const int frow = lane & 15;
    const int fq = (lane >> 4) ^ ((frow >> 1) & 3);

    const unsigned short* gA = A1 + (size_t)(co0 + srow) * 1024 + sq * 8;
    const unsigned short* gB0 = B1 + (size_t)(m0 + srow) * 1024 + sq * 8;
    const unsigned short* gB1 = B1 + (size_t)(m0 + 64 + srow) * 1024 + sq * 8;

    f32x4 acc[2][4];
    #pragma unroll
    for (int i = 0; i < 2; ++i)
        #pragma unroll
        for (int j = 0; j < 4; ++j) acc[i][j] = (f32x4){0.f, 0.f, 0.f, 0.f};

    for (int k0 = 0; k0 < 1024; k0 += 32) {
        gl16(gA + k0,            &sA[0][tid * 8]);
        gl16(gA + 262144 + k0,   &sA[1][tid * 8]);
        gl16(gA + 524288 + k0,   &sA[2][tid * 8]);
        gl16(gB0 + k0, &sB[tid * 8]);
        gl16(gB1 + k0, &sB[(256 + tid) * 8]);
        __syncthreads();
        bf16x8 af[3][2], bfr[4];
        #pragma unroll
        for (int s = 0; s < 3; ++s)
            #pragma unroll
            for (int fr = 0; fr < 2; ++fr)
                af[s][fr] = *(const bf16x8*)&sA[s][(wr * 32 + fr * 16 + frow) * 32 + fq * 8];
        #pragma unroll
        for (int fc = 0; fc < 4; ++fc)
            bfr[fc] = *(const bf16x8*)&sB[(wc * 64 + fc * 16 + frow) * 32 + fq * 8];
        #pragma unroll
        for (int s = 0; s < 3; ++s)
            #pragma unroll
            for (int fr = 0; fr < 2; ++fr)
                #pragma unroll
                for (int fc = 0; fc < 4; ++fc)
                    acc[fr][fc] = MFMA16(af[s][fr], bfr[fc], acc[fr][fc]);
        __syncthreads();
    }
    // epilogue: relu -> bn2 -> sign -> b2p NHWC (interior)
    #pragma unroll
    for (int fc = 0; fc < 4; ++fc) {
        int m = m0 + wc * 64 + fc * 16 + frow;
        int n = m / 196, p = m - n * 196;
        int y = p / 14, xx = p - y * 14;
        size_t ob = ((size_t)(n * 256 + (y + 1) * 16 + (xx + 1))) * 256;
        #pragma unroll
        for (int fr = 0; fr < 2; ++fr) {
            int co = co0 + wr * 32 + fr * 16 + (lane >> 4) * 4;
            unsigned short o[4];
            #pragma unroll
            for (int r = 0; r < 4; ++r) {
                float sc = g2[co + r] * (1.0f / sqrtf(va2[co + r] + EPS));
                float sh = be2[co + r] - mu2[co + r] * sc;
                float h = fmaxf(acc[fr][fc][r], 0.f);
                float t = h * sc + sh;
                o[r] = (t > 0.f) ? 0x3F80 : ((t < 0.f) ? 0xBF80 : 0);
            }
            ushort4 pk; pk.x = o[0]; pk.y = o[1]; pk.z = o[2]; pk.w = o[3];
            *(ushort4*)&b2p[ob + co] = pk;
        }
    }
}

// ---------------- gemm2: conv2 3x3 implicit GEMM, K=9*256, 3 splits -> b3 --
__global__ __launch_bounds__(256, 2) void k_gemm2(
    const unsigned short* __restrict__ A2, const unsigned short* __restrict__ b2p,
    const float* __restrict__ g3, const float* __restrict__ be3,
    const float* __restrict__ mu3, const float* __restrict__ va3,
    unsigned short* __restrict__ b3)
{
    __shared__ unsigned short sA[3][2048];
    __shared__ unsigned short sB[4096];
    const int tid = threadIdx.x;
    const int co0 = blockIdx.x * 64;
    const int m0  = blockIdx.y * 128;
    const int nB  = m0 >> 8;
    const int sp0 = m0 & 255;
    const int lane = tid & 63, w = tid >> 6;
    const int wr = w & 1, wc = w >> 1;
    const int srow = tid >> 2;
    const int sq = (tid & 3) ^ ((tid >> 3) & 3);
    const int frow = lane & 15;
    const int fq = (lane >> 4) ^ ((frow >> 1) & 3);

    const long bbase = (long)(nB * 256 + sp0) * 256;

    f32x4 acc[2][4];
    #pragma unroll
    for (int i = 0; i < 2; ++i)
        #pragma unroll
        for (int j = 0; j < 4; ++j) acc[i][j] = (f32x4){0.f, 0.f, 0.f, 0.f};

    for (int tap = 0; tap < 9; ++tap) {
        int dy = tap / 3, dx = tap - dy * 3;
        int toff = (dy - 1) * 16 + (dx - 1);
        const unsigned short* gA = A2 + (size_t)(co0 + srow) * 2304 + tap * 256 + sq * 8;
        const long brow0 = bbase + (long)toff * 256 + (long)srow * 256 + sq * 8;
        for (int ci0 = 0; ci0 < 256; ci0 += 32) {
            gl16(gA + ci0,           &sA[0][tid * 8]);
            gl16(gA + 589824 + ci0,  &sA[1][tid * 8]);
            gl16(gA + 1179648 + ci0, &sA[2][tid * 8]);
            gl16(b2p + brow0 + ci0,             &sB[tid * 8]);
            gl16(b2p + brow0 + 64 * 256 + ci0,  &sB[(256 + tid) * 8]);
            __syncthreads();
            bf16x8 af[3][2], bfr[4];
            #pragma unroll
            for (int s = 0; s < 3; ++s)
                #pragma unroll
                for (int fr = 0; fr < 2; ++fr)
                    af[s][fr] = *(const bf16x8*)&sA[s][(wr * 32 + fr * 16 + frow) * 32 + fq * 8];
            #pragma unroll
            for (int fc = 0; fc < 4; ++fc)
                bfr[fc] = *(const bf16x8*)&sB[(wc * 64 + fc * 16 + frow) * 32 + fq * 8];
            #pragma unroll
            for (int s = 0; s < 3; ++s)
                #pragma unroll
                for (int fr = 0; fr < 2; ++fr)
                    #pragma unroll
                    for (int fc = 0; fc < 4; ++fc)
                        acc[fr][fc] = MFMA16(af[s][fr], bfr[fc], acc[fr][fc]);
            __syncthreads();
        }
    }
    // epilogue: relu -> bn3 -> sign -> b3 NHWC (valid positions only)
    #pragma unroll
    for (int fc = 0; fc < 4; ++fc) {
        int m = m0 + wc * 64 + fc * 16 + frow;
        int sp = m & 255, nn = m >> 8;
        int y = sp >> 4, xx = sp & 15;
        if (y >= 1 && y <= 14 && xx >= 1 && xx <= 14) {
            int p = (y - 1) * 14 + (xx - 1);
            size_t ob = ((size_t)nn * 196 + p) * 256;
            #pragma unroll
            for (int fr = 0; fr < 2; ++fr) {
                int co = co0 + wr * 32 + fr * 16 + (lane >> 4) * 4;
                unsigned short o[4];
                #pragma unroll
                for (int r = 0; r < 4; ++r) {
                    float sc = g3[co + r] * (1.0f / sqrtf(va3[co + r] + EPS));
                    float sh = be3[co + r] - mu3[co + r] * sc;
                    float h = fmaxf(acc[fr][fc][r], 0.f);
                    float t = h * sc + sh;
                    o[r] = (t > 0.f) ? 0x3F80 : ((t < 0.f) ? 0xBF80 : 0);
                }
                ushort4 pk; pk.x = o[0]; pk.y = o[1]; pk.z = o[2]; pk.w = o[3];
                *(ushort4*)&b3[ob + co] = pk;
            }
        }
    }
}

// ---------------- gemm3: conv3 1x1, K=256, 1 split, +residual+relu --------
// BM=128 BN=128; 4 waves 2x2, each 64x64
__global__ __launch_bounds__(256, 2) void k_gemm3(
    const unsigned short* __restrict__ A3, const unsigned short* __restrict__ B3,
    const float* __restrict__ xres, float* __restrict__ out)
{
    __shared__ unsigned short sA[4096];
    __shared__ unsigned short sB[4096];
    const int tid = threadIdx.x;
    const int co0 = blockIdx.x * 128;
    const int m0  = blockIdx.y * 128;
    const int lane = tid & 63, w = tid >> 6;
    const int wr = w >> 1, wc = w & 1;
    const int srow = tid >> 2;
    const int sq = (tid & 3) ^ ((tid >> 3) & 3);
    const int frow = lane & 15;
    const int fq = (lane >> 4) ^ ((frow >> 1) & 3);

    f32x4 acc[4][4];
    #pragma unroll
    for (int i = 0; i < 4; ++i)
        #pragma unroll
        for (int j = 0; j < 4; ++j) acc[i][j] = (f32x4){0.f, 0.f, 0.f, 0.f};

    for (int k0 = 0; k0 < 256; k0 += 32) {
        gl16(A3 + (size_t)(co0 + srow) * 256 + k0 + sq * 8,      &sA[tid * 8]);
        gl16(A3 + (size_t)(co0 + 64 + srow) * 256 + k0 + sq * 8, &sA[(256 + tid) * 8]);
        gl16(B3 + (size_t)(m0 + srow) * 256 + k0 + sq * 8,       &sB[tid * 8]);
        gl16(B3 + (size_t)(m0 + 64 + srow) * 256 + k0 + sq * 8,  &sB[(256 + tid) * 8]);
        __syncthreads();
        bf16x8 af[4], bfr[4];
        #pragma unroll
        for (int fr = 0; fr < 4; ++fr)
            af[fr] = *(const bf16x8*)&sA[(wr * 64 + fr * 16 + frow) * 32 + fq * 8];
        #pragma unroll
        for (int fc = 0; fc < 4; ++fc)
            bfr[fc] = *(const bf16x8*)&sB[(wc * 64 + fc * 16 + frow) * 32 + fq * 8];
        #pragma unroll
        for (int fr = 0; fr < 4; ++fr)
            #pragma unroll
            for (int fc = 0; fc < 4; ++fc)
                acc[fr][fc] = MFMA16(af[fr], bfr[fc], acc[fr][fc]);
        __syncthreads();
    }
    #pragma unroll
    for (int fc = 0; fc < 4; ++fc) {
        int m = m0 + wc * 64 + fc * 16 + frow;
        int n = m / 196, p = m - n * 196;
        #pragma unroll
        for (int fr = 0; fr < 4; ++fr) {
            int co = co0 + wr * 64 + fr * 16 + (lane >> 4) * 4;
            size_t idx = ((size_t)n * 1024 + co) * 196 + p;
            #pragma unroll
            for (int r = 0; r < 4; ++r)
                out[idx + (size_t)r * 196] =
                    fmaxf(acc[fr][fc][r] + xres[idx + (size_t)r * 196], 0.f);
        }
    }
}

extern "C" void kernel_launch(void* const* d_in, const int* in_sizes, int n_in,
                              void* d_out, int out_size, void* d_ws, size_t ws_size,
                              hipStream_t stream) {
    const float* x   = (const float*)d_in[0];
    const float* g1  = (const float*)d_in[1];
    const float* be1 = (const float*)d_in[2];
    const float* mu1 = (const float*)d_in[3];
    const float* va1 = (const float*)d_in[4];
    const float* W1  = (const float*)d_in[5];
    const float* g2  = (const float*)d_in[6];
    const float* be2 = (const float*)d_in[7];
    const float* mu2 = (const float*)d_in[8];
    const float* va2 = (const float*)d_in[9];
    const float* W2  = (const float*)d_in[10];
    const float* g3  = (const float*)d_in[11];
    const float* be3 = (const float*)d_in[12];
    const float* mu3 = (const float*)d_in[13];
    const float* va3 = (const float*)d_in[14];
    const float* W3  = (const float*)d_in[15];
    float* out = (float*)d_out;

    char* p = (char*)d_ws;
    unsigned short* A1 = (unsigned short*)p;            p += 3 * 262144 * 2;       // 1.5 MB
    unsigned short* A2 = (unsigned short*)p;            p += 3 * 589824 * 2;       // 3.4 MB
    unsigned short* A3 = (unsigned short*)p;            p += 262144 * 2;           // 0.5 MB
    unsigned short* b1 = (unsigned short*)p;            p += (size_t)12544 * 1024 * 2; // 25.7 MB
    p += 16384;                                          // guard before b2p
    unsigned short* b2p = (unsigned short*)p;           p += (size_t)64 * 256 * 256 * 2; // 33.5 MB
    p += 16384;                                          // guard after
    unsigned short* b3 = (unsigned short*)p;            // 6.4 MB

    k_prep<<<2304, 256, 0, stream>>>(W1, W2, W3, A1, A2, A3);
    k_act1<<<dim3(64, 8), 256, 0, stream>>>(x, g1, be1, mu1, va1, b1);
    k_zb<<<480, 256, 0, stream>>>(b2p);
    k_gemm1<<<dim3(4, 98), 256, 0, stream>>>(A1, b1, g2, be2, mu2, va2, b2p);
    k_gemm2<<<dim3(4, 128), 256, 0, stream>>>(A2, b2p, g3, be3, mu3, va3, b3);
    k_gemm3<<<dim3(8, 98), 256, 0, stream>>>(A3, b3, x, out);
}

// Round 9
// 267.145 us; speedup vs baseline: 2.9586x; 1.0879x over previous
//
#include <hip/hip_runtime.h>

#define EPS 1e-5f

typedef __attribute__((ext_vector_type(8))) short bf16x8;
typedef __attribute__((ext_vector_type(4))) float f32x4;

#define MFMA16(a, b, c) __builtin_amdgcn_mfma_f32_16x16x32_bf16(a, b, c, 0, 0, 0)

__device__ __forceinline__ void gl16(const void* g, void* l) {
    __builtin_amdgcn_global_load_lds(
        (const __attribute__((address_space(1))) unsigned int*)g,
        (__attribute__((address_space(3))) unsigned int*)l, 16, 0, 0);
}

__device__ __forceinline__ unsigned short f2bf(float f) {
    unsigned u = __float_as_uint(f);
    unsigned r = (u + 0x7FFFu + ((u >> 16) & 1u)) >> 16;
    return (unsigned short)r;
}
__device__ __forceinline__ float bf2f(unsigned short h) {
    return __uint_as_float(((unsigned)h) << 16);
}

// ws layout:
// A1: 3x[256][1024] bf16 splits; A2: 3x[256][2304] (k'=tap*256+ci); A3: [1024][256]
// sc2/sh2/sc3/sh3: folded bn params (f32[256] each)
// b1  NHWC: [12544][1024] bf16
// b2p NHWC padded: [64][256(sp=16x16)][256(ci)] bf16, 16KB guards both sides
// b3  NHWC: [12544][256] bf16

// ============ merged pre-kernel: act1 | prep | zero-border ============
// blocks [0,512): bn1+sign NCHW->NHWC;  [512,2816): weight splits + bn folds;
// [2816,3296): zero b2p border ring
__global__ __launch_bounds__(256, 2) void k_pre(
    const float* __restrict__ x,
    const float* __restrict__ g1, const float* __restrict__ be1,
    const float* __restrict__ mu1, const float* __restrict__ va1,
    const float* __restrict__ W1,
    const float* __restrict__ g2, const float* __restrict__ be2,
    const float* __restrict__ mu2, const float* __restrict__ va2,
    const float* __restrict__ W2,
    const float* __restrict__ g3, const float* __restrict__ be3,
    const float* __restrict__ mu3, const float* __restrict__ va3,
    const float* __restrict__ W3,
    unsigned short* __restrict__ A1, unsigned short* __restrict__ A2,
    unsigned short* __restrict__ A3,
    float* __restrict__ sc2, float* __restrict__ sh2,
    float* __restrict__ sc3, float* __restrict__ sh3,
    unsigned short* __restrict__ b1, unsigned short* __restrict__ b2p)
{
    __shared__ unsigned short tile[128 * 197];
    __shared__ float ssc[128], ssh[128];
    const int wg = blockIdx.x;
    const int tid = threadIdx.x;

    if (wg < 512) {
        // ---- act1: bn1 + sign, NCHW f32 -> NHWC bf16 ----
        const int n = wg >> 3, c0 = (wg & 7) * 128;
        if (tid < 128) {
            int c = c0 + tid;
            float sc = g1[c] * (1.0f / sqrtf(va1[c] + EPS));
            ssc[tid] = sc;
            ssh[tid] = be1[c] - mu1[c] * sc;
        }
        __syncthreads();
        const float4* xp4 = (const float4*)(x + ((size_t)n * 1024 + c0) * 196);
        for (int it = 0; it < 25; ++it) {
            int e = it * 256 + tid;              // float4 index, 6272 total
            if (e < 6272) {
                int c = e / 49, q = e - c * 49, p = q * 4;
                float4 xv = xp4[e];
                float sc = ssc[c], sh = ssh[c];
                float t0 = xv.x * sc + sh, t1 = xv.y * sc + sh;
                float t2 = xv.z * sc + sh, t3 = xv.w * sc + sh;
                unsigned short* tp = &tile[c * 197 + p];
                tp[0] = (t0 > 0.f) ? 0x3F80 : ((t0 < 0.f) ? 0xBF80 : 0);
                tp[1] = (t1 > 0.f) ? 0x3F80 : ((t1 < 0.f) ? 0xBF80 : 0);
                tp[2] = (t2 > 0.f) ? 0x3F80 : ((t2 < 0.f) ? 0xBF80 : 0);
                tp[3] = (t3 > 0.f) ? 0x3F80 : ((t3 < 0.f) ? 0xBF80 : 0);
            }
        }
        __syncthreads();
        const int pr = tid >> 4, cg = (tid & 15) * 8;
        for (int it = 0; it < 13; ++it) {
            int p = it * 16 + pr;
            if (p < 196) {
                unsigned short vals[8];
                #pragma unroll
                for (int j = 0; j < 8; ++j) vals[j] = tile[(cg + j) * 197 + p];
                uint4 pk;
                pk.x = (unsigned)vals[0] | ((unsigned)vals[1] << 16);
                pk.y = (unsigned)vals[2] | ((unsigned)vals[3] << 16);
                pk.z = (unsigned)vals[4] | ((unsigned)vals[5] << 16);
                pk.w = (unsigned)vals[6] | ((unsigned)vals[7] << 16);
                *(uint4*)&b1[((size_t)n * 196 + p) * 1024 + c0 + cg] = pk;
            }
        }
    } else if (wg < 2816) {
        // ---- prep: weight splits + bn folds ----
        int i = (wg - 512) * 256 + tid;          // [0, 589824)
        if (i < 262144) {
            float w = W1[i];
            unsigned short h1 = f2bf(w); float r1 = w - bf2f(h1);
            unsigned short h2 = f2bf(r1); float r2 = r1 - bf2f(h2);
            unsigned short h3 = f2bf(r2);
            A1[i] = h1; A1[262144 + i] = h2; A1[524288 + i] = h3;
            A3[i] = f2bf(W3[i]);
        }
        {
            int co = i / 2304, k = i - co * 2304;
            int ci = k / 9, tap = k - ci * 9;
            int o = co * 2304 + tap * 256 + ci;
            float w = W2[i];
            unsigned short h1 = f2bf(w); float r1 = w - bf2f(h1);
            unsigned short h2 = f2bf(r1); float r2 = r1 - bf2f(h2);
            unsigned short h3 = f2bf(r2);
            A2[o] = h1; A2[589824 + o] = h2; A2[1179648 + o] = h3;
        }
        if (i < 256) {
            float s2 = g2[i] * (1.0f / sqrtf(va2[i] + EPS));
            sc2[i] = s2; sh2[i] = be2[i] - mu2[i] * s2;
            float s3 = g3[i] * (1.0f / sqrtf(va3[i] + EPS));
            sc3[i] = s3; sh3[i] = be3[i] - mu3[i] * s3;
        }
    } else {
        // ---- zero border ring of b2p ----
        int t = (wg - 2816) * 256 + tid;
        if (t < 122880) {
            int ci8 = t & 31;
            int tb = t >> 5;
            int bidx = tb % 60, n = tb / 60;
            int sp;
            if (bidx < 16) sp = bidx;
            else if (bidx < 32) sp = 240 + (bidx - 16);
            else { int s2 = bidx - 32; sp = ((s2 >> 1) + 1) * 16 + (s2 & 1) * 15; }
            ulonglong2 z; z.x = 0; z.y = 0;
            *(ulonglong2*)&b2p[((size_t)(n * 256 + sp)) * 256 + ci8 * 8] = z;
        }
    }
}

// ============ gemm1: conv1 1x1, K=1024, 3 splits -> b2p ============
// BM=64(co) BN=128(m) BK=32, double-buffered; grid 392 (1D, XCD-swizzled)
__global__ __launch_bounds__(256, 2) void k_gemm1(
    const unsigned short* __restrict__ A1, const unsigned short* __restrict__ B1,
    const float* __restrict__ sc2, const float* __restrict__ sh2,
    unsigned short* __restrict__ b2p)
{
    __shared__ unsigned short sA[2][3][2048];
    __shared__ unsigned short sB[2][4096];
    const int tid = threadIdx.x;
    const int wg = blockIdx.x;                   // 392 = 8*49
    const int r = (wg & 7) * 49 + (wg >> 3);
    const int co0 = (r & 3) * 64;
    const int m0  = (r >> 2) * 128;
    const int lane = tid & 63, w = tid >> 6;
    const int wr = w & 1, wc = w >> 1;
    const int srow = tid >> 2;
    const int sq = (tid & 3) ^ ((tid >> 3) & 3);
    const int frow = lane & 15;
    const int fq = (lane >> 4) ^ ((frow >> 1) & 3);

    const unsigned short* gA  = A1 + (size_t)(co0 + srow) * 1024 + sq * 8;
    const unsigned short* gB0 = B1 + (size_t)(m0 + srow) * 1024 + sq * 8;
    const unsigned short* gB1 = B1 + (size_t)(m0 + 64 + srow) * 1024 + sq * 8;

    auto STAGE = [&](int t, int c) {
        int k0 = t << 5;
        gl16(gA + k0,          &sA[c][0][tid * 8]);
        gl16(gA + 262144 + k0, &sA[c][1][tid * 8]);
        gl16(gA + 524288 + k0, &sA[c][2][tid * 8]);
        gl16(gB0 + k0, &sB[c][tid * 8]);
        gl16(gB1 + k0, &sB[c][2048 + tid * 8]);
    };

    f32x4 acc[2][4];
    #pragma unroll
    for (int i = 0; i < 2; ++i)
        #pragma unroll
        for (int j = 0; j < 4; ++j) acc[i][j] = (f32x4){0.f, 0.f, 0.f, 0.f};

    STAGE(0, 0);
    __syncthreads();
    int cur = 0;
    for (int t = 0; t < 32; ++t) {
        if (t < 31) STAGE(t + 1, cur ^ 1);
        bf16x8 af[3][2], bfr[4];
        #pragma unroll
        for (int s = 0; s < 3; ++s)
            #pragma unroll
            for (int fr = 0; fr < 2; ++fr)
                af[s][fr] = *(const bf16x8*)&sA[cur][s][(wr * 32 + fr * 16 + frow) * 32 + fq * 8];
        #pragma unroll
        for (int fc = 0; fc < 4; ++fc)
            bfr[fc] = *(const bf16x8*)&sB[cur][(wc * 64 + fc * 16 + frow) * 32 + fq * 8];
        #pragma unroll
        for (int s = 0; s < 3; ++s)
            #pragma unroll
            for (int fr = 0; fr < 2; ++fr)
                #pragma unroll
                for (int fc = 0; fc < 4; ++fc)
                    acc[fr][fc] = MFMA16(af[s][fr], bfr[fc], acc[fr][fc]);
        __syncthreads();
        cur ^= 1;
    }
    // epilogue: relu -> bn2(folded) -> sign -> b2p NHWC (interior)
    #pragma unroll
    for (int fc = 0; fc < 4; ++fc) {
        int m = m0 + wc * 64 + fc * 16 + frow;
        int n = m / 196, p = m - n * 196;
        int y = p / 14, xx = p - y * 14;
        size_t ob = ((size_t)(n * 256 + (y + 1) * 16 + (xx + 1))) * 256;
        #pragma unroll
        for (int fr = 0; fr < 2; ++fr) {
            int co = co0 + wr * 32 + fr * 16 + (lane >> 4) * 4;
            unsigned short o[4];
            #pragma unroll
            for (int q = 0; q < 4; ++q) {
                float h = fmaxf(acc[fr][fc][q], 0.f);
                float t = h * sc2[co + q] + sh2[co + q];
                o[q] = (t > 0.f) ? 0x3F80 : ((t < 0.f) ? 0xBF80 : 0);
            }
            ushort4 pk; pk.x = o[0]; pk.y = o[1]; pk.z = o[2]; pk.w = o[3];
            *(ushort4*)&b2p[ob + co] = pk;
        }
    }
}

// ============ gemm2: conv2 3x3 implicit GEMM, 72 k-steps, dbuf ============
__global__ __launch_bounds__(256, 2) void k_gemm2(
    const unsigned short* __restrict__ A2, const unsigned short* __restrict__ b2p,
    const float* __restrict__ sc3, const float* __restrict__ sh3,
    unsigned short* __restrict__ b3)
{
    __shared__ unsigned short sA[2][3][2048];
    __shared__ unsigned short sB[2][4096];
    const int tid = threadIdx.x;
    const int wg = blockIdx.x;                   // 512 = 8*64
    const int r = (wg & 7) * 64 + (wg >> 3);
    const int co0 = (r & 3) * 64;
    const int m0  = (r >> 2) * 128;
    const int nB  = m0 >> 8;
    const int sp0 = m0 & 255;
    const int lane = tid & 63, w = tid >> 6;
    const int wr = w & 1, wc = w >> 1;
    const int srow = tid >> 2;
    const int sq = (tid & 3) ^ ((tid >> 3) & 3);
    const int frow = lane & 15;
    const int fq = (lane >> 4) ^ ((frow >> 1) & 3);

    const long bbase = (long)(nB * 256 + sp0) * 256;

    auto STAGE = [&](int t, int c) {
        int tap = t >> 3, ci0 = (t & 7) << 5;
        int dy = (tap * 11) >> 5, dx = tap - dy * 3;   // tap/3, tap%3 for 0..8
        int toff = (dy - 1) * 16 + dx - 1;
        const unsigned short* gA = A2 + (size_t)(co0 + srow) * 2304 + tap * 256 + ci0 + sq * 8;
        gl16(gA,           &sA[c][0][tid * 8]);
        gl16(gA + 589824,  &sA[c][1][tid * 8]);
        gl16(gA + 1179648, &sA[c][2][tid * 8]);
        long boff = bbase + (long)(toff + srow) * 256 + ci0 + sq * 8;
        gl16(b2p + boff,             &sB[c][tid * 8]);
        gl16(b2p + boff + 64 * 256,  &sB[c][2048 + tid * 8]);
    };

    f32x4 acc[2][4];
    #pragma unroll
    for (int i = 0; i < 2; ++i)
        #pragma unroll
        for (int j = 0; j < 4; ++j) acc[i][j] = (f32x4){0.f, 0.f, 0.f, 0.f};

    STAGE(0, 0);
    __syncthreads();
    int cur = 0;
    for (int t = 0; t < 72; ++t) {
        if (t < 71) STAGE(t + 1, cur ^ 1);
        bf16x8 af[3][2], bfr[4];
        #pragma unroll
        for (int s = 0; s < 3; ++s)
            #pragma unroll
            for (int fr = 0; fr < 2; ++fr)
                af[s][fr] = *(const bf16x8*)&sA[cur][s][(wr * 32 + fr * 16 + frow) * 32 + fq * 8];
        #pragma unroll
        for (int fc = 0; fc < 4; ++fc)
            bfr[fc] = *(const bf16x8*)&sB[cur][(wc * 64 + fc * 16 + frow) * 32 + fq * 8];
        #pragma unroll
        for (int s = 0; s < 3; ++s)
            #pragma unroll
            for (int fr = 0; fr < 2; ++fr)
                #pragma unroll
                for (int fc = 0; fc < 4; ++fc)
                    acc[fr][fc] = MFMA16(af[s][fr], bfr[fc], acc[fr][fc]);
        __syncthreads();
        cur ^= 1;
    }
    // epilogue: relu -> bn3(folded) -> sign -> b3 NHWC (valid positions only)
    #pragma unroll
    for (int fc = 0; fc < 4; ++fc) {
        int m = m0 + wc * 64 + fc * 16 + frow;
        int sp = m & 255, nn = m >> 8;
        int y = sp >> 4, xx = sp & 15;
        if (y >= 1 && y <= 14 && xx >= 1 && xx <= 14) {
            int p = (y - 1) * 14 + (xx - 1);
            size_t ob = ((size_t)nn * 196 + p) * 256;
            #pragma unroll
            for (int fr = 0; fr < 2; ++fr) {
                int co = co0 + wr * 32 + fr * 16 + (lane >> 4) * 4;
                unsigned short o[4];
                #pragma unroll
                for (int q = 0; q < 4; ++q) {
                    float h = fmaxf(acc[fr][fc][q], 0.f);
                    float t = h * sc3[co + q] + sh3[co + q];
                    o[q] = (t > 0.f) ? 0x3F80 : ((t < 0.f) ? 0xBF80 : 0);
                }
                ushort4 pk; pk.x = o[0]; pk.y = o[1]; pk.z = o[2]; pk.w = o[3];
                *(ushort4*)&b3[ob + co] = pk;
            }
        }
    }
}

// ============ gemm3: conv3 1x1, K=256, +residual+relu, dbuf ============
// BM=128 BN=128; 4 waves 2x2, each 64x64; grid 784 (1D, XCD-swizzled)
__global__ __launch_bounds__(256, 3) void k_gemm3(
    const unsigned short* __restrict__ A3, const unsigned short* __restrict__ B3,
    const float* __restrict__ xres, float* __restrict__ out)
{
    __shared__ unsigned short sA[2][4096];
    __shared__ unsigned short sB[2][4096];
    const int tid = threadIdx.x;
    const int wg = blockIdx.x;                   // 784 = 8*98
    const int r = (wg & 7) * 98 + (wg >> 3);
    const int co0 = (r & 7) * 128;
    const int m0  = (r >> 3) * 128;
    const int lane = tid & 63, w = tid >> 6;
    const int wr = w >> 1, wc = w & 1;
    const int srow = tid >> 2;
    const int sq = (tid & 3) ^ ((tid >> 3) & 3);
    const int frow = lane & 15;
    const int fq = (lane >> 4) ^ ((frow >> 1) & 3);

    auto STAGE = [&](int t, int c) {
        int k0 = t << 5;
        gl16(A3 + (size_t)(co0 + srow) * 256 + k0 + sq * 8,      &sA[c][tid * 8]);
        gl16(A3 + (size_t)(co0 + 64 + srow) * 256 + k0 + sq * 8, &sA[c][2048 + tid * 8]);
        gl16(B3 + (size_t)(m0 + srow) * 256 + k0 + sq * 8,       &sB[c][tid * 8]);
        gl16(B3 + (size_t)(m0 + 64 + srow) * 256 + k0 + sq * 8,  &sB[c][2048 + tid * 8]);
    };

    f32x4 acc[4][4];
    #pragma unroll
    for (int i = 0; i < 4; ++i)
        #pragma unroll
        for (int j = 0; j < 4; ++j) acc[i][j] = (f32x4){0.f, 0.f, 0.f, 0.f};

    STAGE(0, 0);
    __syncthreads();
    int cur = 0;
    for (int t = 0; t < 8; ++t) {
        if (t < 7) STAGE(t + 1, cur ^ 1);
        bf16x8 af[4], bfr[4];
        #pragma unroll
        for (int fr = 0; fr < 4; ++fr)
            af[fr] = *(const bf16x8*)&sA[cur][(wr * 64 + fr * 16 + frow) * 32 + fq * 8];
        #pragma unroll
        for (int fc = 0; fc < 4; ++fc)
            bfr[fc] = *(const bf16x8*)&sB[cur][(wc * 64 + fc * 16 + frow) * 32 + fq * 8];
        #pragma unroll
        for (int fr = 0; fr < 4; ++fr)
            #pragma unroll
            for (int fc = 0; fc < 4; ++fc)
                acc[fr][fc] = MFMA16(af[fr], bfr[fc], acc[fr][fc]);
        __syncthreads();
        cur ^= 1;
    }
    #pragma unroll
    for (int fc = 0; fc < 4; ++fc) {
        int m = m0 + wc * 64 + fc * 16 + frow;
        int n = m / 196, p = m - n * 196;
        #pragma unroll
        for (int fr = 0; fr < 4; ++fr) {
            int co = co0 + wr * 64 + fr * 16 + (lane >> 4) * 4;
            size_t idx = ((size_t)n * 1024 + co) * 196 + p;
            #pragma unroll
            for (int q = 0; q < 4; ++q)
                out[idx + (size_t)q * 196] =
                    fmaxf(acc[fr][fc][q] + xres[idx + (size_t)q * 196], 0.f);
        }
    }
}

extern "C" void kernel_launch(void* const* d_in, const int* in_sizes, int n_in,
                              void* d_out, int out_size, void* d_ws, size_t ws_size,
                              hipStream_t stream) {
    const float* x   = (const float*)d_in[0];
    const float* g1  = (const float*)d_in[1];
    const float* be1 = (const float*)d_in[2];
    const float* mu1 = (const float*)d_in[3];
    const float* va1 = (const float*)d_in[4];
    const float* W1  = (const float*)d_in[5];
    const float* g2  = (const float*)d_in[6];
    const float* be2 = (const float*)d_in[7];
    const float* mu2 = (const float*)d_in[8];
    const float* va2 = (const float*)d_in[9];
    const float* W2  = (const float*)d_in[10];
    const float* g3  = (const float*)d_in[11];
    const float* be3 = (const float*)d_in[12];
    const float* mu3 = (const float*)d_in[13];
    const float* va3 = (const float*)d_in[14];
    const float* W3  = (const float*)d_in[15];
    float* out = (float*)d_out;

    char* p = (char*)d_ws;
    unsigned short* A1 = (unsigned short*)p;  p += 3 * 262144 * 2;       // 1.5 MB
    unsigned short* A2 = (unsigned short*)p;  p += 3 * 589824 * 2;       // 3.4 MB
    unsigned short* A3 = (unsigned short*)p;  p += 262144 * 2;           // 0.5 MB
    float* sc2 = (float*)p;                   p += 256 * 4;
    float* sh2 = (float*)p;                   p += 256 * 4;
    float* sc3 = (float*)p;                   p += 256 * 4;
    float* sh3 = (float*)p;                   p += 256 * 4;
    unsigned short* b1 = (unsigned short*)p;  p += (size_t)12544 * 1024 * 2; // 25.7 MB
    p += 16384;                                // guard before b2p
    unsigned short* b2p = (unsigned short*)p; p += (size_t)64 * 256 * 256 * 2; // 33.5 MB
    p += 16384;                                // guard after
    unsigned short* b3 = (unsigned short*)p;   // 6.4 MB

    k_pre<<<3296, 256, 0, stream>>>(x, g1, be1, mu1, va1, W1,
                                    g2, be2, mu2, va2, W2,
                                    g3, be3, mu3, va3, W3,
                                    A1, A2, A3, sc2, sh2, sc3, sh3, b1, b2p);
    k_gemm1<<<392, 256, 0, stream>>>(A1, b1, sc2, sh2, b2p);
    k_gemm2<<<512, 256, 0, stream>>>(A2, b2p, sc3, sh3, b3);
    k_gemm3<<<784, 256, 0, stream>>>(A3, b3, x, out);
}

// Round 12
// 254.128 us; speedup vs baseline: 3.1102x; 1.0512x over previous
//
#include <hip/hip_runtime.h>

#define EPS 1e-5f

typedef __attribute__((ext_vector_type(8))) short bf16x8;
typedef __attribute__((ext_vector_type(4))) float f32x4;

#define MFMA16(a, b, c) __builtin_amdgcn_mfma_f32_16x16x32_bf16(a, b, c, 0, 0, 0)

__device__ __forceinline__ void gl16(const void* g, void* l) {
    __builtin_amdgcn_global_load_lds(
        (const __attribute__((address_space(1))) unsigned int*)g,
        (__attribute__((address_space(3))) unsigned int*)l, 16, 0, 0);
}

__device__ __forceinline__ unsigned short f2bf(float f) {
    unsigned u = __float_as_uint(f);
    unsigned r = (u + 0x7FFFu + ((u >> 16) & 1u)) >> 16;
    return (unsigned short)r;
}
__device__ __forceinline__ float bf2f(unsigned short h) {
    return __uint_as_float(((unsigned)h) << 16);
}

// ws layout:
// A1: 3x[256][1024] bf16 splits; A2: 3x[256][2304] (k'=tap*256+ci); A3: [1024][256]
// sc2/sh2/sc3/sh3: folded bn params (f32[256] each)
// b1  NHWC: [12544][1024] bf16
// b2p NHWC padded: [64][256(sp=16x16)][256(ci)] bf16, 16KB guards both sides
// b3  NHWC: [12544][256] bf16

// ============ merged pre-kernel: act1 | prep | zero-border ============
__global__ __launch_bounds__(256, 2) void k_pre(
    const float* __restrict__ x,
    const float* __restrict__ g1, const float* __restrict__ be1,
    const float* __restrict__ mu1, const float* __restrict__ va1,
    const float* __restrict__ W1,
    const float* __restrict__ g2, const float* __restrict__ be2,
    const float* __restrict__ mu2, const float* __restrict__ va2,
    const float* __restrict__ W2,
    const float* __restrict__ g3, const float* __restrict__ be3,
    const float* __restrict__ mu3, const float* __restrict__ va3,
    const float* __restrict__ W3,
    unsigned short* __restrict__ A1, unsigned short* __restrict__ A2,
    unsigned short* __restrict__ A3,
    float* __restrict__ sc2, float* __restrict__ sh2,
    float* __restrict__ sc3, float* __restrict__ sh3,
    unsigned short* __restrict__ b1, unsigned short* __restrict__ b2p)
{
    __shared__ unsigned short tile[128 * 197];
    __shared__ float ssc[128], ssh[128];
    const int wg = blockIdx.x;
    const int tid = threadIdx.x;

    if (wg < 512) {
        // ---- act1: bn1 + sign, NCHW f32 -> NHWC bf16 ----
        const int n = wg >> 3, c0 = (wg & 7) * 128;
        if (tid < 128) {
            int c = c0 + tid;
            float sc = g1[c] * (1.0f / sqrtf(va1[c] + EPS));
            ssc[tid] = sc;
            ssh[tid] = be1[c] - mu1[c] * sc;
        }
        __syncthreads();
        const float4* xp4 = (const float4*)(x + ((size_t)n * 1024 + c0) * 196);
        for (int it = 0; it < 25; ++it) {
            int e = it * 256 + tid;              // float4 index, 6272 total
            if (e < 6272) {
                int c = e / 49, q = e - c * 49, p = q * 4;
                float4 xv = xp4[e];
                float sc = ssc[c], sh = ssh[c];
                float t0 = xv.x * sc + sh, t1 = xv.y * sc + sh;
                float t2 = xv.z * sc + sh, t3 = xv.w * sc + sh;
                unsigned short* tp = &tile[c * 197 + p];
                tp[0] = (t0 > 0.f) ? 0x3F80 : ((t0 < 0.f) ? 0xBF80 : 0);
                tp[1] = (t1 > 0.f) ? 0x3F80 : ((t1 < 0.f) ? 0xBF80 : 0);
                tp[2] = (t2 > 0.f) ? 0x3F80 : ((t2 < 0.f) ? 0xBF80 : 0);
                tp[3] = (t3 > 0.f) ? 0x3F80 : ((t3 < 0.f) ? 0xBF80 : 0);
            }
        }
        __syncthreads();
        const int pr = tid >> 4, cg = (tid & 15) * 8;
        for (int it = 0; it < 13; ++it) {
            int p = it * 16 + pr;
            if (p < 196) {
                unsigned short vals[8];
                #pragma unroll
                for (int j = 0; j < 8; ++j) vals[j] = tile[(cg + j) * 197 + p];
                uint4 pk;
                pk.x = (unsigned)vals[0] | ((unsigned)vals[1] << 16);
                pk.y = (unsigned)vals[2] | ((unsigned)vals[3] << 16);
                pk.z = (unsigned)vals[4] | ((unsigned)vals[5] << 16);
                pk.w = (unsigned)vals[6] | ((unsigned)vals[7] << 16);
                *(uint4*)&b1[((size_t)n * 196 + p) * 1024 + c0 + cg] = pk;
            }
        }
    } else if (wg < 2816) {
        // ---- prep: weight splits + bn folds ----
        int i = (wg - 512) * 256 + tid;          // [0, 589824)
        if (i < 262144) {
            float w = W1[i];
            unsigned short h1 = f2bf(w); float r1 = w - bf2f(h1);
            unsigned short h2 = f2bf(r1); float r2 = r1 - bf2f(h2);
            unsigned short h3 = f2bf(r2);
            A1[i] = h1; A1[262144 + i] = h2; A1[524288 + i] = h3;
            A3[i] = f2bf(W3[i]);
        }
        {
            int co = i / 2304, k = i - co * 2304;
            int ci = k / 9, tap = k - ci * 9;
            int o = co * 2304 + tap * 256 + ci;
            float w = W2[i];
            unsigned short h1 = f2bf(w); float r1 = w - bf2f(h1);
            unsigned short h2 = f2bf(r1); float r2 = r1 - bf2f(h2);
            unsigned short h3 = f2bf(r2);
            A2[o] = h1; A2[589824 + o] = h2; A2[1179648 + o] = h3;
        }
        if (i < 256) {
            float s2 = g2[i] * (1.0f / sqrtf(va2[i] + EPS));
            sc2[i] = s2; sh2[i] = be2[i] - mu2[i] * s2;
            float s3 = g3[i] * (1.0f / sqrtf(va3[i] + EPS));
            sc3[i] = s3; sh3[i] = be3[i] - mu3[i] * s3;
        }
    } else {
        // ---- zero border ring of b2p ----
        int t = (wg - 2816) * 256 + tid;
        if (t < 122880) {
            int ci8 = t & 31;
            int tb = t >> 5;
            int bidx = tb % 60, n = tb / 60;
            int sp;
            if (bidx < 16) sp = bidx;
            else if (bidx < 32) sp = 240 + (bidx - 16);
            else { int s2 = bidx - 32; sp = ((s2 >> 1) + 1) * 16 + (s2 & 1) * 15; }
            ulonglong2 z; z.x = 0; z.y = 0;
            *(ulonglong2*)&b2p[((size_t)(n * 256 + sp)) * 256 + ci8 * 8] = z;
        }
    }
}

// ============ gemm1: conv1 1x1, K=1024, 3 splits -> b2p ============
// BM=64(co) BN=128(m) BK=32; ring-3 LDS, counted vmcnt (T3+T4); grid 392
__global__ __launch_bounds__(256, 2) void k_gemm1(
    const unsigned short* __restrict__ A1, const unsigned short* __restrict__ B1,
    const float* __restrict__ sc2, const float* __restrict__ sh2,
    unsigned short* __restrict__ b2p)
{
    __shared__ unsigned short sA[3][3][2048];
    __shared__ unsigned short sB[3][4096];
    const int tid = threadIdx.x;
    const int wg = blockIdx.x;                   // 392 = 8*49
    const int r = (wg & 7) * 49 + (wg >> 3);
    const int co0 = (r & 3) * 64;
    const int m0  = (r >> 2) * 128;
    const int lane = tid & 63, w = tid >> 6;
    const int wr = w & 1, wc = w >> 1;
    const int srow = tid >> 2;
    const int sq = (tid & 3) ^ ((tid >> 3) & 3);
    const int frow = lane & 15;
    const int fq = (lane >> 4) ^ ((frow >> 1) & 3);

    const unsigned short* gA  = A1 + (size_t)(co0 + srow) * 1024 + sq * 8;
    const unsigned short* gB0 = B1 + (size_t)(m0 + srow) * 1024 + sq * 8;
    const unsigned short* gB1 = B1 + (size_t)(m0 + 64 + srow) * 1024 + sq * 8;

    auto STAGE = [&](int t, int c) {     // 5 vmcnt ops per call
        int k0 = t << 5;
        gl16(gA + k0,          &sA[c][0][tid * 8]);
        gl16(gA + 262144 + k0, &sA[c][1][tid * 8]);
        gl16(gA + 524288 + k0, &sA[c][2][tid * 8]);
        gl16(gB0 + k0, &sB[c][tid * 8]);
        gl16(gB1 + k0, &sB[c][2048 + tid * 8]);
    };

    f32x4 acc[2][4];
    #pragma unroll
    for (int i = 0; i < 2; ++i)
        #pragma unroll
        for (int j = 0; j < 4; ++j) acc[i][j] = (f32x4){0.f, 0.f, 0.f, 0.f};

    STAGE(0, 0);
    STAGE(1, 1);
    int cur = 0;
    for (int t = 0; t < 32; ++t) {
        if (t < 30) {
            int stg = cur + 2; if (stg >= 3) stg -= 3;
            STAGE(t + 2, stg);
            asm volatile("s_waitcnt vmcnt(10)" ::: "memory");   // buf[cur] ready
        } else if (t == 30) {
            asm volatile("s_waitcnt vmcnt(5)" ::: "memory");
        } else {
            asm volatile("s_waitcnt vmcnt(0)" ::: "memory");
        }
        __builtin_amdgcn_s_barrier();
        bf16x8 af[3][2], bfr[4];
        #pragma unroll
        for (int s = 0; s < 3; ++s)
            #pragma unroll
            for (int fr = 0; fr < 2; ++fr)
                af[s][fr] = *(const bf16x8*)&sA[cur][s][(wr * 32 + fr * 16 + frow) * 32 + fq * 8];
        #pragma unroll
        for (int fc = 0; fc < 4; ++fc)
            bfr[fc] = *(const bf16x8*)&sB[cur][(wc * 64 + fc * 16 + frow) * 32 + fq * 8];
        #pragma unroll
        for (int s = 0; s < 3; ++s)
            #pragma unroll
            for (int fr = 0; fr < 2; ++fr)
                #pragma unroll
                for (int fc = 0; fc < 4; ++fc)
                    acc[fr][fc] = MFMA16(af[s][fr], bfr[fc], acc[fr][fc]);
        __builtin_amdgcn_s_barrier();            // WAR: done reading buf[cur]
        cur = (cur == 2) ? 0 : cur + 1;
    }
    // epilogue: relu -> bn2(folded) -> sign -> b2p NHWC (interior)
    #pragma unroll
    for (int fc = 0; fc < 4; ++fc) {
        int m = m0 + wc * 64 + fc * 16 + frow;
        int n = m / 196, p = m - n * 196;
        int y = p / 14, xx = p - y * 14;
        size_t ob = ((size_t)(n * 256 + (y + 1) * 16 + (xx + 1))) * 256;
        #pragma unroll
        for (int fr = 0; fr < 2; ++fr) {
            int co = co0 + wr * 32 + fr * 16 + (lane >> 4) * 4;
            unsigned short o[4];
            #pragma unroll
            for (int q = 0; q < 4; ++q) {
                float h = fmaxf(acc[fr][fc][q], 0.f);
                float t = h * sc2[co + q] + sh2[co + q];
                o[q] = (t > 0.f) ? 0x3F80 : ((t < 0.f) ? 0xBF80 : 0);
            }
            ushort4 pk; pk.x = o[0]; pk.y = o[1]; pk.z = o[2]; pk.w = o[3];
            *(ushort4*)&b2p[ob + co] = pk;
        }
    }
}

// ============ gemm2: conv2 3x3 implicit GEMM, 72 k-steps, ring-3 ============
__global__ __launch_bounds__(256, 2) void k_gemm2(
    const unsigned short* __restrict__ A2, const unsigned short* __restrict__ b2p,
    const float* __restrict__ sc3, const float* __restrict__ sh3,
    unsigned short* __restrict__ b3)
{
    __shared__ unsigned short sA[3][3][2048];
    __shared__ unsigned short sB[3][4096];
    const int tid = threadIdx.x;
    const int wg = blockIdx.x;                   // 512 = 8*64
    const int r = (wg & 7) * 64 + (wg >> 3);
    const int co0 = (r & 3) * 64;
    const int m0  = (r >> 2) * 128;
    const int nB  = m0 >> 8;
    const int sp0 = m0 & 255;
    const int lane = tid & 63, w = tid >> 6;
    const int wr = w & 1, wc = w >> 1;
    const int srow = tid >> 2;
    const int sq = (tid & 3) ^ ((tid >> 3) & 3);
    const int frow = lane & 15;
    const int fq = (lane >> 4) ^ ((frow >> 1) & 3);

    const long bbase = (long)(nB * 256 + sp0) * 256;

    auto STAGE = [&](int t, int c) {     // 5 vmcnt ops per call
        int tap = t >> 3, ci0 = (t & 7) << 5;
        int dy = (tap * 11) >> 5, dx = tap - dy * 3;   // tap/3, tap%3 for 0..8
        int toff = (dy - 1) * 16 + dx - 1;
        const unsigned short* gA = A2 + (size_t)(co0 + srow) * 2304 + tap * 256 + ci0 + sq * 8;
        gl16(gA,           &sA[c][0][tid * 8]);
        gl16(gA + 589824,  &sA[c][1][tid * 8]);
        gl16(gA + 1179648, &sA[c][2][tid * 8]);
        long boff = bbase + (long)(toff + srow) * 256 + ci0 + sq * 8;
        gl16(b2p + boff,             &sB[c][tid * 8]);
        gl16(b2p + boff + 64 * 256,  &sB[c][2048 + tid * 8]);
    };

    f32x4 acc[2][4];
    #pragma unroll
    for (int i = 0; i < 2; ++i)
        #pragma unroll
        for (int j = 0; j < 4; ++j) acc[i][j] = (f32x4){0.f, 0.f, 0.f, 0.f};

    STAGE(0, 0);
    STAGE(1, 1);
    int cur = 0;
    for (int t = 0; t < 72; ++t) {
        if (t < 70) {
            int stg = cur + 2; if (stg >= 3) stg -= 3;
            STAGE(t + 2, stg);
            asm volatile("s_waitcnt vmcnt(10)" ::: "memory");   // buf[cur] ready
        } else if (t == 70) {
            asm volatile("s_waitcnt vmcnt(5)" ::: "memory");
        } else {
            asm volatile("s_waitcnt vmcnt(0)" ::: "memory");
        }
        __builtin_amdgcn_s_barrier();
        bf16x8 af[3][2], bfr[4];
        #pragma unroll
        for (int s = 0; s < 3; ++s)
            #pragma unroll
            for (int fr = 0; fr < 2; ++fr)
                af[s][fr] = *(const bf16x8*)&sA[cur][s][(wr * 32 + fr * 16 + frow) * 32 + fq * 8];
        #pragma unroll
        for (int fc = 0; fc < 4; ++fc)
            bfr[fc] = *(const bf16x8*)&sB[cur][(wc * 64 + fc * 16 + frow) * 32 + fq * 8];
        #pragma unroll
        for (int s = 0; s < 3; ++s)
            #pragma unroll
            for (int fr = 0; fr < 2; ++fr)
                #pragma unroll
                for (int fc = 0; fc < 4; ++fc)
                    acc[fr][fc] = MFMA16(af[s][fr], bfr[fc], acc[fr][fc]);
        __builtin_amdgcn_s_barrier();            // WAR: done reading buf[cur]
        cur = (cur == 2) ? 0 : cur + 1;
    }
    // epilogue: relu -> bn3(folded) -> sign -> b3 NHWC (valid positions only)
    #pragma unroll
    for (int fc = 0; fc < 4; ++fc) {
        int m = m0 + wc * 64 + fc * 16 + frow;
        int sp = m & 255, nn = m >> 8;
        int y = sp >> 4, xx = sp & 15;
        if (y >= 1 && y <= 14 && xx >= 1 && xx <= 14) {
            int p = (y - 1) * 14 + (xx - 1);
            size_t ob = ((size_t)nn * 196 + p) * 256;
            #pragma unroll
            for (int fr = 0; fr < 2; ++fr) {
                int co = co0 + wr * 32 + fr * 16 + (lane >> 4) * 4;
                unsigned short o[4];
                #pragma unroll
                for (int q = 0; q < 4; ++q) {
                    float h = fmaxf(acc[fr][fc][q], 0.f);
                    float t = h * sc3[co + q] + sh3[co + q];
                    o[q] = (t > 0.f) ? 0x3F80 : ((t < 0.f) ? 0xBF80 : 0);
                }
                ushort4 pk; pk.x = o[0]; pk.y = o[1]; pk.z = o[2]; pk.w = o[3];
                *(ushort4*)&b3[ob + co] = pk;
            }
        }
    }
}

// ============ gemm3: conv3 1x1, K=256, +residual+relu, ring-3 ============
// BM=128 BN=128; 4 waves 2x2, each 64x64; grid 784
__global__ __launch_bounds__(256, 3) void k_gemm3(
    const unsigned short* __restrict__ A3, const unsigned short* __restrict__ B3,
    const float* __restrict__ xres, float* __restrict__ out)
{
    __shared__ unsigned short sA[3][4096];
    __shared__ unsigned short sB[3][4096];
    const int tid = threadIdx.x;
    const int wg = blockIdx.x;                   // 784 = 8*98
    const int r = (wg & 7) * 98 + (wg >> 3);
    const int co0 = (r & 7) * 128;
    const int m0  = (r >> 3) * 128;
    const int lane = tid & 63, w = tid >> 6;
    const int wr = w >> 1, wc = w & 1;
    const int srow = tid >> 2;
    const int sq = (tid & 3) ^ ((tid >> 3) & 3);
    const int frow = lane & 15;
    const int fq = (lane >> 4) ^ ((frow >> 1) & 3);

    auto STAGE = [&](int t, int c) {     // 4 vmcnt ops per call
        int k0 = t << 5;
        gl16(A3 + (size_t)(co0 + srow) * 256 + k0 + sq * 8,      &sA[c][tid * 8]);
        gl16(A3 + (size_t)(co0 + 64 + srow) * 256 + k0 + sq * 8, &sA[c][2048 + tid * 8]);
        gl16(B3 + (size_t)(m0 + srow) * 256 + k0 + sq * 8,       &sB[c][tid * 8]);
        gl16(B3 + (size_t)(m0 + 64 + srow) * 256 + k0 + sq * 8,  &sB[c][2048 + tid * 8]);
    };

    f32x4 acc[4][4];
    #pragma unroll
    for (int i = 0; i < 4; ++i)
        #pragma unroll
        for (int j = 0; j < 4; ++j) acc[i][j] = (f32x4){0.f, 0.f, 0.f, 0.f};

    STAGE(0, 0);
    STAGE(1, 1);
    int cur = 0;
    for (int t = 0; t < 8; ++t) {
        if (t < 6) {
            int stg = cur + 2; if (stg >= 3) stg -= 3;
            STAGE(t + 2, stg);
            asm volatile("s_waitcnt vmcnt(8)" ::: "memory");    // buf[cur] ready
        } else if (t == 6) {
            asm volatile("s_waitcnt vmcnt(4)" ::: "memory");
        } else {
            asm volatile("s_waitcnt vmcnt(0)" ::: "memory");
        }
        __builtin_amdgcn_s_barrier();
        bf16x8 af[4], bfr[4];
        #pragma unroll
        for (int fr = 0; fr < 4; ++fr)
            af[fr] = *(const bf16x8*)&sA[cur][(wr * 64 + fr * 16 + frow) * 32 + fq * 8];
        #pragma unroll
        for (int fc = 0; fc < 4; ++fc)
            bfr[fc] = *(const bf16x8*)&sB[cur][(wc * 64 + fc * 16 + frow) * 32 + fq * 8];
        #pragma unroll
        for (int fr = 0; fr < 4; ++fr)
            #pragma unroll
            for (int fc = 0; fc < 4; ++fc)
                acc[fr][fc] = MFMA16(af[fr], bfr[fc], acc[fr][fc]);
        __builtin_amdgcn_s_barrier();            // WAR: done reading buf[cur]
        cur = (cur == 2) ? 0 : cur + 1;
    }
    #pragma unroll
    for (int fc = 0; fc < 4; ++fc) {
        int m = m0 + wc * 64 + fc * 16 + frow;
        int n = m / 196, p = m - n * 196;
        #pragma unroll
        for (int fr = 0; fr < 4; ++fr) {
            int co = co0 + wr * 64 + fr * 16 + (lane >> 4) * 4;
            size_t idx = ((size_t)n * 1024 + co) * 196 + p;
            #pragma unroll
            for (int q = 0; q < 4; ++q)
                out[idx + (size_t)q * 196] =
                    fmaxf(acc[fr][fc][q] + xres[idx + (size_t)q * 196], 0.f);
        }
    }
}

extern "C" void kernel_launch(void* const* d_in, const int* in_sizes, int n_in,
                              void* d_out, int out_size, void* d_ws, size_t ws_size,
                              hipStream_t stream) {
    const float* x   = (const float*)d_in[0];
    const float* g1  = (const float*)d_in[1];
    const float* be1 = (const float*)d_in[2];
    const float* mu1 = (const float*)d_in[3];
    const float* va1 = (const float*)d_in[4];
    const float* W1  = (const float*)d_in[5];
    const float* g2  = (const float*)d_in[6];
    const float* be2 = (const float*)d_in[7];
    const float* mu2 = (const float*)d_in[8];
    const float* va2 = (const float*)d_in[9];
    const float* W2  = (const float*)d_in[10];
    const float* g3  = (const float*)d_in[11];
    const float* be3 = (const float*)d_in[12];
    const float* mu3 = (const float*)d_in[13];
    const float* va3 = (const float*)d_in[14];
    const float* W3  = (const float*)d_in[15];
    float* out = (float*)d_out;

    char* p = (char*)d_ws;
    unsigned short* A1 = (unsigned short*)p;  p += 3 * 262144 * 2;       // 1.5 MB
    unsigned short* A2 = (unsigned short*)p;  p += 3 * 589824 * 2;       // 3.4 MB
    unsigned short* A3 = (unsigned short*)p;  p += 262144 * 2;           // 0.5 MB
    float* sc2 = (float*)p;                   p += 256 * 4;
    float* sh2 = (float*)p;                   p += 256 * 4;
    float* sc3 = (float*)p;                   p += 256 * 4;
    float* sh3 = (float*)p;                   p += 256 * 4;
    unsigned short* b1 = (unsigned short*)p;  p += (size_t)12544 * 1024 * 2; // 25.7 MB
    p += 16384;                                // guard before b2p
    unsigned short* b2p = (unsigned short*)p; p += (size_t)64 * 256 * 256 * 2; // 33.5 MB
    p += 16384;                                // guard after
    unsigned short* b3 = (unsigned short*)p;   // 6.4 MB

    k_pre<<<3296, 256, 0, stream>>>(x, g1, be1, mu1, va1, W1,
                                    g2, be2, mu2, va2, W2,
                                    g3, be3, mu3, va3, W3,
                                    A1, A2, A3, sc2, sh2, sc3, sh3, b1, b2p);
    k_gemm1<<<392, 256, 0, stream>>>(A1, b1, sc2, sh2, b2p);
    k_gemm2<<<512, 256, 0, stream>>>(A2, b2p, sc3, sh3, b3);
    k_gemm3<<<784, 256, 0, stream>>>(A3, b3, x, out);
}